// Round 1
// baseline (384.835 us; speedup 1.0000x reference)
//
#include <hip/hip_runtime.h>

using f32x4  = __attribute__((ext_vector_type(4))) float;
using bf16x8 = __attribute__((ext_vector_type(8))) short;
using u16x8  = __attribute__((ext_vector_type(8))) unsigned short;
using u16x4  = __attribute__((ext_vector_type(4))) unsigned short;

static __device__ __forceinline__ unsigned short f2bf(float f) {
  unsigned int u = __builtin_bit_cast(unsigned int, f);
  u += 0x7FFFu + ((u >> 16) & 1u);
  return (unsigned short)(u >> 16);
}
static __device__ __forceinline__ float bf2f(unsigned short h) {
  unsigned int u = ((unsigned int)h) << 16;
  return __builtin_bit_cast(float, u);
}

// ---------------------------------------------------------------------------
// W [1024 i][1024 o] f32  ->  WT_hi/WT_lo [1024 o][1024 i] bf16 (transposed)
// ---------------------------------------------------------------------------
__global__ __launch_bounds__(256) void convert_w_kernel(
    const float* __restrict__ Wk, const float* __restrict__ Wv,
    const float* __restrict__ Wq, unsigned short* __restrict__ WThi,
    unsigned short* __restrict__ WTlo) {
  __shared__ float sW[64][65];
  const int z = blockIdx.z;
  const float* W = (z == 0) ? Wk : (z == 1) ? Wv : Wq;
  unsigned short* oh = WThi + (size_t)z * 1024 * 1024;
  unsigned short* ol = WTlo + (size_t)z * 1024 * 1024;
  const int ti = blockIdx.x * 64;  // i tile
  const int tj = blockIdx.y * 64;  // o tile
  const int tid = threadIdx.x;
#pragma unroll
  for (int it = 0; it < 4; ++it) {
    int idx = tid + it * 256;
    int r = idx >> 4, c = (idx & 15) << 2;
    f32x4 v = *(const f32x4*)&W[(size_t)(ti + r) * 1024 + tj + c];
    sW[r][c] = v[0]; sW[r][c + 1] = v[1]; sW[r][c + 2] = v[2]; sW[r][c + 3] = v[3];
  }
  __syncthreads();
#pragma unroll
  for (int it = 0; it < 4; ++it) {
    int idx = tid + it * 256;
    int ro = idx >> 4, ci = (idx & 15) << 2;
    u16x4 h, l;
#pragma unroll
    for (int e = 0; e < 4; ++e) {
      float v = sW[ci + e][ro];
      unsigned short hh = f2bf(v);
      h[e] = hh;
      l[e] = f2bf(v - bf2f(hh));
    }
    *(u16x4*)&oh[(size_t)(tj + ro) * 1024 + ti + ci] = h;
    *(u16x4*)&ol[(size_t)(tj + ro) * 1024 + ti + ci] = l;
  }
}

// ---------------------------------------------------------------------------
// Projection GEMM: C[8192 x 1024] = X[8192 x 1024](f32) @ W (via WT hi/lo bf16)
// 3-term split-bf16 MFMA. Output stored as bf16 hi (+lo if write_lo).
// ---------------------------------------------------------------------------
__global__ __launch_bounds__(256, 2) void proj_kernel(
    const float* __restrict__ X, const unsigned short* __restrict__ BTh,
    const unsigned short* __restrict__ BTl, unsigned short* __restrict__ Ohi,
    unsigned short* __restrict__ Olo, int write_lo) {
  constexpr int K = 1024, N = 1024, LDP = 40;
  __shared__ unsigned short sAh[128 * LDP], sAl[128 * LDP];
  __shared__ unsigned short sBh[128 * LDP], sBl[128 * LDP];
  const int tid = threadIdx.x, lane = tid & 63, wave = tid >> 6;
  const int wr = (wave >> 1) << 6, wc = (wave & 1) << 6;
  const int bm = blockIdx.y << 7, bn = blockIdx.x << 7;
  const int srow = tid >> 1, scg = (tid & 1) << 4;
  const float* pA = X + (size_t)(bm + srow) * K + scg;
  const unsigned short* pBh = BTh + (size_t)(bn + srow) * K + scg;
  const unsigned short* pBl = BTl + (size_t)(bn + srow) * K + scg;
  f32x4 acc[4][4] = {};
  f32x4 a0, a1, a2, a3;
  u16x8 b0, b1, c0, c1;
  auto gload = [&](int k0) {
    const f32x4* ap = (const f32x4*)(pA + k0);
    a0 = ap[0]; a1 = ap[1]; a2 = ap[2]; a3 = ap[3];
    const u16x8* bp = (const u16x8*)(pBh + k0);
    b0 = bp[0]; b1 = bp[1];
    const u16x8* cp = (const u16x8*)(pBl + k0);
    c0 = cp[0]; c1 = cp[1];
  };
  gload(0);
  const int frow = lane & 15, koff = (lane >> 4) << 3;
  for (int k0 = 0; k0 < K; k0 += 32) {
    __syncthreads();
    {
      float av[16];
      *(f32x4*)&av[0] = a0; *(f32x4*)&av[4] = a1;
      *(f32x4*)&av[8] = a2; *(f32x4*)&av[12] = a3;
      u16x8 h0, h1, l0, l1;
#pragma unroll
      for (int e = 0; e < 8; ++e) {
        unsigned short hh = f2bf(av[e]);
        h0[e] = hh; l0[e] = f2bf(av[e] - bf2f(hh));
        unsigned short hh2 = f2bf(av[8 + e]);
        h1[e] = hh2; l1[e] = f2bf(av[8 + e] - bf2f(hh2));
      }
      *(u16x8*)&sAh[srow * LDP + scg] = h0; *(u16x8*)&sAh[srow * LDP + scg + 8] = h1;
      *(u16x8*)&sAl[srow * LDP + scg] = l0; *(u16x8*)&sAl[srow * LDP + scg + 8] = l1;
      *(u16x8*)&sBh[srow * LDP + scg] = b0; *(u16x8*)&sBh[srow * LDP + scg + 8] = b1;
      *(u16x8*)&sBl[srow * LDP + scg] = c0; *(u16x8*)&sBl[srow * LDP + scg + 8] = c1;
    }
    __syncthreads();
    if (k0 + 32 < K) gload(k0 + 32);
    bf16x8 fAh[4], fAl[4], fBh[4], fBl[4];
#pragma unroll
    for (int i = 0; i < 4; ++i) {
      fAh[i] = *(const bf16x8*)&sAh[(wr + i * 16 + frow) * LDP + koff];
      fAl[i] = *(const bf16x8*)&sAl[(wr + i * 16 + frow) * LDP + koff];
      fBh[i] = *(const bf16x8*)&sBh[(wc + i * 16 + frow) * LDP + koff];
      fBl[i] = *(const bf16x8*)&sBl[(wc + i * 16 + frow) * LDP + koff];
    }
#pragma unroll
    for (int i = 0; i < 4; ++i)
#pragma unroll
      for (int j = 0; j < 4; ++j) {
        acc[i][j] = __builtin_amdgcn_mfma_f32_16x16x32_bf16(fAh[i], fBh[j], acc[i][j], 0, 0, 0);
        acc[i][j] = __builtin_amdgcn_mfma_f32_16x16x32_bf16(fAh[i], fBl[j], acc[i][j], 0, 0, 0);
        acc[i][j] = __builtin_amdgcn_mfma_f32_16x16x32_bf16(fAl[i], fBh[j], acc[i][j], 0, 0, 0);
      }
  }
  const int erow = bm + wr + ((lane >> 4) << 2), ecol = bn + wc + (lane & 15);
#pragma unroll
  for (int i = 0; i < 4; ++i)
#pragma unroll
    for (int j = 0; j < 4; ++j)
#pragma unroll
      for (int e = 0; e < 4; ++e) {
        size_t off = (size_t)(erow + i * 16 + e) * N + (ecol + j * 16);
        float v = acc[i][j][e];
        unsigned short hh = f2bf(v);
        Ohi[off] = hh;
        if (write_lo) Olo[off] = f2bf(v - bf2f(hh));
      }
}

// ---------------------------------------------------------------------------
// V [b][2048 s][1024 o] bf16 -> VT [b][1024 o][2048 s] bf16
// ---------------------------------------------------------------------------
__global__ __launch_bounds__(256) void transpose_v_kernel(
    const unsigned short* __restrict__ V, unsigned short* __restrict__ VT) {
  __shared__ unsigned short sV[64][72];
  const int ox = blockIdx.x, sy = blockIdx.y, b = blockIdx.z;
  const int tid = threadIdx.x;
#pragma unroll
  for (int it = 0; it < 2; ++it) {
    int idx = tid + it * 256;
    int r = idx >> 3, c8 = (idx & 7) << 3;
    u16x8 v = *(const u16x8*)&V[((size_t)b * 2048 + sy * 64 + r) * 1024 + ox * 64 + c8];
#pragma unroll
    for (int e = 0; e < 8; ++e) sV[r][c8 + e] = v[e];
  }
  __syncthreads();
#pragma unroll
  for (int it = 0; it < 2; ++it) {
    int idx = tid + it * 256;
    int ro = idx >> 3, cs = (idx & 7) << 3;
    u16x8 w;
#pragma unroll
    for (int e = 0; e < 8; ++e) w[e] = sV[cs + e][ro];
    *(u16x8*)&VT[((size_t)b * 1024 + ox * 64 + ro) * 2048 + sy * 64 + cs] = w;
  }
}

// ---------------------------------------------------------------------------
// scores[b][q][k] = sum_d Q[b,q,d] * K[b,k,d]   (raw, unscaled; f32 out)
// 3-term split-bf16. Lower-triangle tiles only.
// ---------------------------------------------------------------------------
__global__ __launch_bounds__(256, 2) void scores_kernel(
    const unsigned short* __restrict__ Qh, const unsigned short* __restrict__ Ql,
    const unsigned short* __restrict__ Kh, const unsigned short* __restrict__ Kl,
    float* __restrict__ Sc) {
  constexpr int D = 1024, LDP = 40;
  const int kb = blockIdx.x, qb = blockIdx.y, b = blockIdx.z;
  if (kb > qb) return;
  __shared__ unsigned short sAh[128 * LDP], sAl[128 * LDP];
  __shared__ unsigned short sBh[128 * LDP], sBl[128 * LDP];
  const int tid = threadIdx.x, lane = tid & 63, wave = tid >> 6;
  const int wr = (wave >> 1) << 6, wc = (wave & 1) << 6;
  const int srow = tid >> 1, scg = (tid & 1) << 4;
  const size_t qbase = ((size_t)b * 2048 + qb * 128 + srow) * D + scg;
  const size_t kbase = ((size_t)b * 2048 + kb * 128 + srow) * D + scg;
  f32x4 acc[4][4] = {};
  u16x8 ra0, ra1, rb0, rb1, rc0, rc1, rd0, rd1;
  auto gload = [&](int k0) {
    ra0 = *(const u16x8*)(Qh + qbase + k0); ra1 = *(const u16x8*)(Qh + qbase + k0 + 8);
    rb0 = *(const u16x8*)(Ql + qbase + k0); rb1 = *(const u16x8*)(Ql + qbase + k0 + 8);
    rc0 = *(const u16x8*)(Kh + kbase + k0); rc1 = *(const u16x8*)(Kh + kbase + k0 + 8);
    rd0 = *(const u16x8*)(Kl + kbase + k0); rd1 = *(const u16x8*)(Kl + kbase + k0 + 8);
  };
  gload(0);
  const int frow = lane & 15, koff = (lane >> 4) << 3;
  for (int k0 = 0; k0 < D; k0 += 32) {
    __syncthreads();
    *(u16x8*)&sAh[srow * LDP + scg] = ra0; *(u16x8*)&sAh[srow * LDP + scg + 8] = ra1;
    *(u16x8*)&sAl[srow * LDP + scg] = rb0; *(u16x8*)&sAl[srow * LDP + scg + 8] = rb1;
    *(u16x8*)&sBh[srow * LDP + scg] = rc0; *(u16x8*)&sBh[srow * LDP + scg + 8] = rc1;
    *(u16x8*)&sBl[srow * LDP + scg] = rd0; *(u16x8*)&sBl[srow * LDP + scg + 8] = rd1;
    __syncthreads();
    if (k0 + 32 < D) gload(k0 + 32);
    bf16x8 fAh[4], fAl[4], fBh[4], fBl[4];
#pragma unroll
    for (int i = 0; i < 4; ++i) {
      fAh[i] = *(const bf16x8*)&sAh[(wr + i * 16 + frow) * LDP + koff];
      fAl[i] = *(const bf16x8*)&sAl[(wr + i * 16 + frow) * LDP + koff];
      fBh[i] = *(const bf16x8*)&sBh[(wc + i * 16 + frow) * LDP + koff];
      fBl[i] = *(const bf16x8*)&sBl[(wc + i * 16 + frow) * LDP + koff];
    }
#pragma unroll
    for (int i = 0; i < 4; ++i)
#pragma unroll
      for (int j = 0; j < 4; ++j) {
        acc[i][j] = __builtin_amdgcn_mfma_f32_16x16x32_bf16(fAh[i], fBh[j], acc[i][j], 0, 0, 0);
        acc[i][j] = __builtin_amdgcn_mfma_f32_16x16x32_bf16(fAh[i], fBl[j], acc[i][j], 0, 0, 0);
        acc[i][j] = __builtin_amdgcn_mfma_f32_16x16x32_bf16(fAl[i], fBh[j], acc[i][j], 0, 0, 0);
      }
  }
  const int erow = qb * 128 + wr + ((lane >> 4) << 2), ecol = kb * 128 + wc + (lane & 15);
#pragma unroll
  for (int i = 0; i < 4; ++i)
#pragma unroll
    for (int j = 0; j < 4; ++j)
#pragma unroll
      for (int e = 0; e < 4; ++e)
        Sc[((size_t)b * 2048 + erow + i * 16 + e) * 2048 + ecol + j * 16] = acc[i][j][e];
}

// ---------------------------------------------------------------------------
// Row softmax with causal mask + 1/sqrt(d) scale. Writes bf16 P in-place over
// the f32 scores buffer (row r's P occupies the first 4KB of row r's 8KB).
// Safe: every thread's reads complete before the first __syncthreads().
// ---------------------------------------------------------------------------
__global__ __launch_bounds__(256) void softmax_kernel(float* __restrict__ Sc) {
  const int row = blockIdx.x;  // b*2048 + q
  const int q = row & 2047;
  const int tid = threadIdx.x, lane = tid & 63, wave = tid >> 6;
  float* srow = Sc + (size_t)row * 2048;
  unsigned short* prow = (unsigned short*)srow;
  const int k0 = tid * 4, k1 = 1024 + tid * 4;
  f32x4 v0 = *(const f32x4*)(srow + k0);
  f32x4 v1 = *(const f32x4*)(srow + k1);
  float m = -3.0e38f;
#pragma unroll
  for (int e = 0; e < 4; ++e) {
    if (k0 + e <= q) m = fmaxf(m, v0[e]);
    if (k1 + e <= q) m = fmaxf(m, v1[e]);
  }
#pragma unroll
  for (int o = 32; o; o >>= 1) m = fmaxf(m, __shfl_xor(m, o));
  __shared__ float redm[4], reds[4];
  if (lane == 0) redm[wave] = m;
  __syncthreads();
  m = fmaxf(fmaxf(redm[0], redm[1]), fmaxf(redm[2], redm[3]));
  const float scale = 0.03125f;  // 1/sqrt(1024)
  float p[8];
  float s = 0.f;
#pragma unroll
  for (int e = 0; e < 4; ++e) {
    p[e] = (k0 + e <= q) ? __expf((v0[e] - m) * scale) : 0.f;
    p[4 + e] = (k1 + e <= q) ? __expf((v1[e] - m) * scale) : 0.f;
    s += p[e] + p[4 + e];
  }
#pragma unroll
  for (int o = 32; o; o >>= 1) s += __shfl_xor(s, o);
  if (lane == 0) reds[wave] = s;
  __syncthreads();
  s = reds[0] + reds[1] + reds[2] + reds[3];
  const float inv = 1.0f / s;
  u16x4 o0, o1;
#pragma unroll
  for (int e = 0; e < 4; ++e) {
    o0[e] = f2bf(p[e] * inv);
    o1[e] = f2bf(p[4 + e] * inv);
  }
  *(u16x4*)&prow[k0] = o0;
  *(u16x4*)&prow[k1] = o1;
}

// ---------------------------------------------------------------------------
// out[b][q][o] = sum_k P[b,q,k] * V[b,k,o]   (P bf16 pitch 4096u, VT bf16)
// Plain bf16 MFMA; K-loop stops at the diagonal block.
// ---------------------------------------------------------------------------
__global__ __launch_bounds__(256, 2) void pv_kernel(
    const unsigned short* __restrict__ P, const unsigned short* __restrict__ VT,
    float* __restrict__ Out) {
  constexpr int LDP = 40;
  __shared__ unsigned short sA[128 * LDP], sB[128 * LDP];
  const int nb = blockIdx.x, qb = blockIdx.y, b = blockIdx.z;
  const int tid = threadIdx.x, lane = tid & 63, wave = tid >> 6;
  const int wr = (wave >> 1) << 6, wc = (wave & 1) << 6;
  const int srow = tid >> 1, scg = (tid & 1) << 4;
  const size_t pbase = ((size_t)b * 2048 + qb * 128 + srow) * 4096 + scg;
  const size_t vbase = ((size_t)b * 1024 + nb * 128 + srow) * 2048 + scg;
  const int kend = (qb + 1) * 128;
  f32x4 acc[4][4] = {};
  u16x8 ra0, ra1, rb0, rb1;
  auto gload = [&](int k0) {
    ra0 = *(const u16x8*)(P + pbase + k0); ra1 = *(const u16x8*)(P + pbase + k0 + 8);
    rb0 = *(const u16x8*)(VT + vbase + k0); rb1 = *(const u16x8*)(VT + vbase + k0 + 8);
  };
  gload(0);
  const int frow = lane & 15, koff = (lane >> 4) << 3;
  for (int k0 = 0; k0 < kend; k0 += 32) {
    __syncthreads();
    *(u16x8*)&sA[srow * LDP + scg] = ra0; *(u16x8*)&sA[srow * LDP + scg + 8] = ra1;
    *(u16x8*)&sB[srow * LDP + scg] = rb0; *(u16x8*)&sB[srow * LDP + scg + 8] = rb1;
    __syncthreads();
    if (k0 + 32 < kend) gload(k0 + 32);
    bf16x8 fA[4], fB[4];
#pragma unroll
    for (int i = 0; i < 4; ++i) {
      fA[i] = *(const bf16x8*)&sA[(wr + i * 16 + frow) * LDP + koff];
      fB[i] = *(const bf16x8*)&sB[(wc + i * 16 + frow) * LDP + koff];
    }
#pragma unroll
    for (int i = 0; i < 4; ++i)
#pragma unroll
      for (int j = 0; j < 4; ++j)
        acc[i][j] = __builtin_amdgcn_mfma_f32_16x16x32_bf16(fA[i], fB[j], acc[i][j], 0, 0, 0);
  }
  const int erow = qb * 128 + wr + ((lane >> 4) << 2), ecol = nb * 128 + wc + (lane & 15);
#pragma unroll
  for (int i = 0; i < 4; ++i)
#pragma unroll
    for (int j = 0; j < 4; ++j)
#pragma unroll
      for (int e = 0; e < 4; ++e)
        Out[((size_t)b * 2048 + erow + i * 16 + e) * 1024 + ecol + j * 16] = acc[i][j][e];
}

// ---------------------------------------------------------------------------
extern "C" void kernel_launch(void* const* d_in, const int* in_sizes, int n_in,
                              void* d_out, int out_size, void* d_ws, size_t ws_size,
                              hipStream_t stream) {
  const float* Xk = (const float*)d_in[0];
  const float* Xv = (const float*)d_in[1];
  const float* Xq = (const float*)d_in[2];
  const float* Wk = (const float*)d_in[3];
  const float* Wv = (const float*)d_in[4];
  const float* Wq = (const float*)d_in[5];
  float* out = (float*)d_out;

  char* ws = (char*)d_ws;
  size_t off = 0;
  auto walloc = [&](size_t bytes) {
    void* p = ws + off;
    off += (bytes + 255) & ~(size_t)255;
    return p;
  };
  unsigned short* WThi = (unsigned short*)walloc(3ull * 1024 * 1024 * 2);
  unsigned short* WTlo = (unsigned short*)walloc(3ull * 1024 * 1024 * 2);
  unsigned short* Qhi = (unsigned short*)walloc(8192ull * 1024 * 2);
  unsigned short* Qlo = (unsigned short*)walloc(8192ull * 1024 * 2);
  unsigned short* Khi = (unsigned short*)walloc(8192ull * 1024 * 2);
  unsigned short* Klo = (unsigned short*)walloc(8192ull * 1024 * 2);
  unsigned short* Vhi = (unsigned short*)walloc(8192ull * 1024 * 2);
  unsigned short* VT = (unsigned short*)walloc(8192ull * 1024 * 2);
  float* Sc = (float*)walloc(4ull * 2048 * 2048 * 4);

  convert_w_kernel<<<dim3(16, 16, 3), 256, 0, stream>>>(Wk, Wv, Wq, WThi, WTlo);
  // z order in WT: 0=K, 1=V, 2=Q
  proj_kernel<<<dim3(8, 64), 256, 0, stream>>>(Xq, WThi + 2u * 1048576u,
                                               WTlo + 2u * 1048576u, Qhi, Qlo, 1);
  proj_kernel<<<dim3(8, 64), 256, 0, stream>>>(Xk, WThi, WTlo, Khi, Klo, 1);
  proj_kernel<<<dim3(8, 64), 256, 0, stream>>>(Xv, WThi + 1u * 1048576u,
                                               WTlo + 1u * 1048576u, Vhi, Vhi, 0);
  transpose_v_kernel<<<dim3(16, 32, 4), 256, 0, stream>>>(Vhi, VT);
  scores_kernel<<<dim3(16, 16, 4), 256, 0, stream>>>(Qhi, Qlo, Khi, Klo, Sc);
  softmax_kernel<<<dim3(8192), 256, 0, stream>>>(Sc);
  pv_kernel<<<dim3(8, 16, 4), 256, 0, stream>>>((const unsigned short*)Sc, VT, out);
}

// Round 2
// 361.958 us; speedup vs baseline: 1.0632x; 1.0632x over previous
//
#include <hip/hip_runtime.h>

using f32x4  = __attribute__((ext_vector_type(4))) float;
using bf16x8 = __attribute__((ext_vector_type(8))) short;
using u16x8  = __attribute__((ext_vector_type(8))) unsigned short;
using u16x4  = __attribute__((ext_vector_type(4))) unsigned short;

static __device__ __forceinline__ unsigned short f2bf(float f) {
  unsigned int u = __builtin_bit_cast(unsigned int, f);
  u += 0x7FFFu + ((u >> 16) & 1u);
  return (unsigned short)(u >> 16);
}
static __device__ __forceinline__ float bf2f(unsigned short h) {
  unsigned int u = ((unsigned int)h) << 16;
  return __builtin_bit_cast(float, u);
}

// async global->LDS, 16B per lane. LDS dest must be wave-uniform base;
// HW appends lane*16.
static __device__ __forceinline__ void gll16(const void* g, void* l) {
  using GPtr = const unsigned int __attribute__((address_space(1)))*;
  using LPtr = unsigned int __attribute__((address_space(3)))*;
  __builtin_amdgcn_global_load_lds((GPtr)(unsigned long long)g,
                                   (LPtr)(unsigned)(unsigned long long)l,
                                   16, 0, 0);
}

// stage one [128][32] bf16 tile (linear, row-major) from global rows of pitch
// `ld` starting at column k0. Each wave stages rows [32w, 32w+32).
static __device__ __forceinline__ void stage_tile(unsigned short* sdst,
                                                  const unsigned short* g,
                                                  size_t ld, int k0, int wave,
                                                  int lane) {
  const int r = lane >> 2, c = (lane & 3) << 3;
#pragma unroll
  for (int i = 0; i < 2; ++i) {
    const unsigned short* gp = g + (size_t)(wave * 32 + i * 16 + r) * ld + (k0 + c);
    unsigned short* lp = sdst + wave * 1024 + i * 512;  // wave-uniform
    gll16(gp, lp);
  }
}

// ---------------------------------------------------------------------------
// W [1024 i][1024 o] f32  ->  WT_hi/WT_lo [1024 o][1024 i] bf16 (transposed)
// ---------------------------------------------------------------------------
__global__ __launch_bounds__(256) void convert_w_kernel(
    const float* __restrict__ Wk, const float* __restrict__ Wv,
    const float* __restrict__ Wq, unsigned short* __restrict__ WThi,
    unsigned short* __restrict__ WTlo) {
  __shared__ float sW[64][65];
  const int z = blockIdx.z;
  const float* W = (z == 0) ? Wk : (z == 1) ? Wv : Wq;
  unsigned short* oh = WThi + (size_t)z * 1024 * 1024;
  unsigned short* ol = WTlo + (size_t)z * 1024 * 1024;
  const int ti = blockIdx.x * 64;  // i tile
  const int tj = blockIdx.y * 64;  // o tile
  const int tid = threadIdx.x;
#pragma unroll
  for (int it = 0; it < 4; ++it) {
    int idx = tid + it * 256;
    int r = idx >> 4, c = (idx & 15) << 2;
    f32x4 v = *(const f32x4*)&W[(size_t)(ti + r) * 1024 + tj + c];
    sW[r][c] = v[0]; sW[r][c + 1] = v[1]; sW[r][c + 2] = v[2]; sW[r][c + 3] = v[3];
  }
  __syncthreads();
#pragma unroll
  for (int it = 0; it < 4; ++it) {
    int idx = tid + it * 256;
    int ro = idx >> 4, ci = (idx & 15) << 2;
    u16x4 h, l;
#pragma unroll
    for (int e = 0; e < 4; ++e) {
      float v = sW[ci + e][ro];
      unsigned short hh = f2bf(v);
      h[e] = hh;
      l[e] = f2bf(v - bf2f(hh));
    }
    *(u16x4*)&oh[(size_t)(tj + ro) * 1024 + ti + ci] = h;
    *(u16x4*)&ol[(size_t)(tj + ro) * 1024 + ti + ci] = l;
  }
}

// ---------------------------------------------------------------------------
// X [8192 x 1024] f32 -> Xh (+Xl for z!=1) bf16, same layout.
// z: 0=keys, 1=values, 2=queries. Xl slots: keys->0, queries->1.
// ---------------------------------------------------------------------------
__global__ __launch_bounds__(256) void convert_x_kernel(
    const float* __restrict__ Xk, const float* __restrict__ Xv,
    const float* __restrict__ Xq, unsigned short* __restrict__ H,
    unsigned short* __restrict__ L) {
  const int z = blockIdx.z;
  const float* X = (z == 0) ? Xk : (z == 1) ? Xv : Xq;
  const size_t base = ((size_t)blockIdx.x * 256 + threadIdx.x) * 8;
  float av[8];
  *(f32x4*)&av[0] = *(const f32x4*)&X[base];
  *(f32x4*)&av[4] = *(const f32x4*)&X[base + 4];
  u16x8 h, l;
#pragma unroll
  for (int e = 0; e < 8; ++e) {
    unsigned short hh = f2bf(av[e]);
    h[e] = hh;
    l[e] = f2bf(av[e] - bf2f(hh));
  }
  *(u16x8*)&H[(size_t)z * 8388608 + base] = h;
  if (z != 1) {
    int lz = (z == 0) ? 0 : 1;
    *(u16x8*)&L[(size_t)lz * 8388608 + base] = l;
  }
}

// ---------------------------------------------------------------------------
// Unified split-bf16 GEMM, m97 structure: 128x128 tile, BK=32, 4 waves,
// global_load_lds staging into linear [128][32] LDS tiles, 2 barriers/K-step.
// C = A * B^T where A rows = output rows, B rows = output cols, both K-major.
// NTERMS: 3 = AhBh+AhBl+AlBh ; 2 = AhBh+AhBl ; 1 = AhBh.
// EPI: 0 = f32 C ; 1 = bf16 hi+lo ; 2 = bf16 hi.
// CAUSAL: skip tiles with bn>bm. PVK: K-loop ends at (bm+1)*128.
// ---------------------------------------------------------------------------
template <int NTERMS, int EPI, bool CAUSAL, bool PVK>
__global__ __launch_bounds__(256, 2) void gemm3_kernel(
    const unsigned short* __restrict__ Ah, const unsigned short* __restrict__ Al,
    const unsigned short* __restrict__ Bh, const unsigned short* __restrict__ Bl,
    size_t lda, size_t ldb, int K,
    float* __restrict__ Cf, unsigned short* __restrict__ Ch,
    unsigned short* __restrict__ Cl, size_t ldc,
    size_t abatch, size_t bbatch, size_t cbatch) {
  constexpr int NTILES = (NTERMS == 3) ? 4 : (NTERMS == 2) ? 3 : 2;
  __shared__ unsigned short smem[NTILES * 4096];
  const int bn = blockIdx.x, bm = blockIdx.y, b = blockIdx.z;
  if (CAUSAL && bn > bm) return;
  const int tid = threadIdx.x, lane = tid & 63, wave = tid >> 6;
  unsigned short* sAh = smem;
  unsigned short* sBh = smem + 4096;
  unsigned short* sBl = smem + 8192;   // NTERMS >= 2
  unsigned short* sAl = smem + 12288;  // NTERMS == 3
  const unsigned short* gA = Ah + abatch * b + (size_t)(bm * 128) * lda;
  const unsigned short* gB = Bh + bbatch * b + (size_t)(bn * 128) * ldb;
  const unsigned short* gAl2 =
      (NTERMS == 3) ? Al + abatch * b + (size_t)(bm * 128) * lda : nullptr;
  const unsigned short* gBl2 =
      (NTERMS >= 2) ? Bl + bbatch * b + (size_t)(bn * 128) * ldb : nullptr;
  const int kend = PVK ? (bm + 1) * 128 : K;
  f32x4 acc[4][4] = {};
  const int wr = (wave >> 1) << 6, wc = (wave & 1) << 6;
  const int frow = lane & 15, koff = (lane >> 4) << 3;
  for (int k0 = 0; k0 < kend; k0 += 32) {
    __syncthreads();  // all waves done reading previous tile
    stage_tile(sAh, gA, lda, k0, wave, lane);
    stage_tile(sBh, gB, ldb, k0, wave, lane);
    if constexpr (NTERMS >= 2) stage_tile(sBl, gBl2, ldb, k0, wave, lane);
    if constexpr (NTERMS == 3) stage_tile(sAl, gAl2, lda, k0, wave, lane);
    __syncthreads();  // staging complete (vmcnt drained before barrier)
    bf16x8 fBh[4], fBl[4];
#pragma unroll
    for (int j = 0; j < 4; ++j) {
      fBh[j] = *(const bf16x8*)&sBh[(wc + j * 16 + frow) * 32 + koff];
      if constexpr (NTERMS >= 2)
        fBl[j] = *(const bf16x8*)&sBl[(wc + j * 16 + frow) * 32 + koff];
    }
#pragma unroll
    for (int i = 0; i < 4; ++i) {
      const bf16x8 ah = *(const bf16x8*)&sAh[(wr + i * 16 + frow) * 32 + koff];
      bf16x8 al = {};
      if constexpr (NTERMS == 3)
        al = *(const bf16x8*)&sAl[(wr + i * 16 + frow) * 32 + koff];
#pragma unroll
      for (int j = 0; j < 4; ++j) {
        acc[i][j] = __builtin_amdgcn_mfma_f32_16x16x32_bf16(ah, fBh[j], acc[i][j], 0, 0, 0);
        if constexpr (NTERMS >= 2)
          acc[i][j] = __builtin_amdgcn_mfma_f32_16x16x32_bf16(ah, fBl[j], acc[i][j], 0, 0, 0);
        if constexpr (NTERMS == 3)
          acc[i][j] = __builtin_amdgcn_mfma_f32_16x16x32_bf16(al, fBh[j], acc[i][j], 0, 0, 0);
      }
    }
  }
  const int erow = bm * 128 + wr + ((lane >> 4) << 2);
  const int ecol = bn * 128 + wc + frow;
  if constexpr (EPI == 0) {
    float* C = Cf + cbatch * b;
#pragma unroll
    for (int i = 0; i < 4; ++i)
#pragma unroll
      for (int j = 0; j < 4; ++j)
#pragma unroll
        for (int e = 0; e < 4; ++e)
          C[(size_t)(erow + i * 16 + e) * ldc + (ecol + j * 16)] = acc[i][j][e];
  } else {
#pragma unroll
    for (int i = 0; i < 4; ++i)
#pragma unroll
      for (int j = 0; j < 4; ++j)
#pragma unroll
        for (int e = 0; e < 4; ++e) {
          size_t off = (size_t)(erow + i * 16 + e) * ldc + (ecol + j * 16);
          float v = acc[i][j][e];
          unsigned short hh = f2bf(v);
          Ch[off] = hh;
          if constexpr (EPI == 1) Cl[off] = f2bf(v - bf2f(hh));
        }
  }
}

// ---------------------------------------------------------------------------
// V [b][2048 s][1024 o] bf16 -> VT [b][1024 o][2048 s] bf16
// ---------------------------------------------------------------------------
__global__ __launch_bounds__(256) void transpose_v_kernel(
    const unsigned short* __restrict__ V, unsigned short* __restrict__ VT) {
  __shared__ unsigned short sV[64][72];
  const int ox = blockIdx.x, sy = blockIdx.y, b = blockIdx.z;
  const int tid = threadIdx.x;
#pragma unroll
  for (int it = 0; it < 2; ++it) {
    int idx = tid + it * 256;
    int r = idx >> 3, c8 = (idx & 7) << 3;
    u16x8 v = *(const u16x8*)&V[((size_t)b * 2048 + sy * 64 + r) * 1024 + ox * 64 + c8];
#pragma unroll
    for (int e = 0; e < 8; ++e) sV[r][c8 + e] = v[e];
  }
  __syncthreads();
#pragma unroll
  for (int it = 0; it < 2; ++it) {
    int idx = tid + it * 256;
    int ro = idx >> 3, cs = (idx & 7) << 3;
    u16x8 w;
#pragma unroll
    for (int e = 0; e < 8; ++e) w[e] = sV[cs + e][ro];
    *(u16x8*)&VT[((size_t)b * 1024 + ox * 64 + ro) * 2048 + sy * 64 + cs] = w;
  }
}

// ---------------------------------------------------------------------------
// Row softmax with causal mask + 1/sqrt(d) scale. Writes bf16 P in-place over
// the f32 scores buffer (row r's P occupies the first 4KB of row r's 8KB).
// Safe: every thread's reads complete before the first __syncthreads().
// ---------------------------------------------------------------------------
__global__ __launch_bounds__(256) void softmax_kernel(float* __restrict__ Sc) {
  const int row = blockIdx.x;  // b*2048 + q
  const int q = row & 2047;
  const int tid = threadIdx.x, lane = tid & 63, wave = tid >> 6;
  float* srow = Sc + (size_t)row * 2048;
  unsigned short* prow = (unsigned short*)srow;
  const int k0 = tid * 4, k1 = 1024 + tid * 4;
  f32x4 v0 = {}, v1 = {};
  if (k0 <= q) v0 = *(const f32x4*)(srow + k0);
  if (k1 <= q) v1 = *(const f32x4*)(srow + k1);
  float m = -3.0e38f;
#pragma unroll
  for (int e = 0; e < 4; ++e) {
    if (k0 + e <= q) m = fmaxf(m, v0[e]);
    if (k1 + e <= q) m = fmaxf(m, v1[e]);
  }
#pragma unroll
  for (int o = 32; o; o >>= 1) m = fmaxf(m, __shfl_xor(m, o));
  __shared__ float redm[4], reds[4];
  if (lane == 0) redm[wave] = m;
  __syncthreads();
  m = fmaxf(fmaxf(redm[0], redm[1]), fmaxf(redm[2], redm[3]));
  const float scale = 0.03125f;  // 1/sqrt(1024)
  float p[8];
  float s = 0.f;
#pragma unroll
  for (int e = 0; e < 4; ++e) {
    p[e] = (k0 + e <= q) ? __expf((v0[e] - m) * scale) : 0.f;
    p[4 + e] = (k1 + e <= q) ? __expf((v1[e] - m) * scale) : 0.f;
    s += p[e] + p[4 + e];
  }
#pragma unroll
  for (int o = 32; o; o >>= 1) s += __shfl_xor(s, o);
  if (lane == 0) reds[wave] = s;
  __syncthreads();
  s = reds[0] + reds[1] + reds[2] + reds[3];
  const float inv = 1.0f / s;
  u16x4 o0, o1;
#pragma unroll
  for (int e = 0; e < 4; ++e) {
    o0[e] = f2bf(p[e] * inv);
    o1[e] = f2bf(p[4 + e] * inv);
  }
  *(u16x4*)&prow[k0] = o0;
  *(u16x4*)&prow[k1] = o1;
}

// ---------------------------------------------------------------------------
extern "C" void kernel_launch(void* const* d_in, const int* in_sizes, int n_in,
                              void* d_out, int out_size, void* d_ws, size_t ws_size,
                              hipStream_t stream) {
  const float* Xk = (const float*)d_in[0];
  const float* Xv = (const float*)d_in[1];
  const float* Xq = (const float*)d_in[2];
  const float* Wk = (const float*)d_in[3];
  const float* Wv = (const float*)d_in[4];
  const float* Wq = (const float*)d_in[5];
  float* out = (float*)d_out;

  char* ws = (char*)d_ws;
  size_t off = 0;
  auto walloc = [&](size_t bytes) {
    void* p = ws + off;
    off += (bytes + 255) & ~(size_t)255;
    return p;
  };
  const size_t XSZ = 8192ull * 1024;  // elements per [8192x1024] matrix
  // X region: dead after the three projections.
  unsigned short* Xh = (unsigned short*)walloc(3 * XSZ * 2);  // [0, 50.3MB)
  unsigned short* Xl = (unsigned short*)walloc(2 * XSZ * 2);  // [50.3, 83.9MB)
  unsigned short* WThi = (unsigned short*)walloc(3ull * 1024 * 1024 * 2);
  unsigned short* WTlo = (unsigned short*)walloc(3ull * 1024 * 1024 * 2);
  unsigned short* Qhi = (unsigned short*)walloc(XSZ * 2);
  unsigned short* Qlo = (unsigned short*)walloc(XSZ * 2);
  unsigned short* Khi = (unsigned short*)walloc(XSZ * 2);
  unsigned short* Klo = (unsigned short*)walloc(XSZ * 2);
  unsigned short* Vhi = (unsigned short*)walloc(XSZ * 2);
  // Aliases into the dead X region (written only after all projs complete):
  float* Sc = (float*)(ws + 0);                              // 67.1MB
  unsigned short* VT = (unsigned short*)(ws + 67108864ull);  // 16.8MB, ends 83.9MB

  convert_w_kernel<<<dim3(16, 16, 3), 256, 0, stream>>>(Wk, Wv, Wq, WThi, WTlo);
  convert_x_kernel<<<dim3(4096, 1, 3), 256, 0, stream>>>(Xk, Xv, Xq, Xh, Xl);

  // Q projection (3-term, hi+lo out)
  gemm3_kernel<3, 1, false, false><<<dim3(8, 64, 1), 256, 0, stream>>>(
      Xh + 2 * XSZ, Xl + 1 * XSZ, WThi + 2u * 1048576u, WTlo + 2u * 1048576u,
      1024, 1024, 1024, nullptr, Qhi, Qlo, 1024, 0, 0, 0);
  // K projection (3-term, hi+lo out)
  gemm3_kernel<3, 1, false, false><<<dim3(8, 64, 1), 256, 0, stream>>>(
      Xh, Xl, WThi, WTlo, 1024, 1024, 1024, nullptr, Khi, Klo, 1024, 0, 0, 0);
  // V projection (2-term: full-precision W, bf16 X; hi out)
  gemm3_kernel<2, 2, false, false><<<dim3(8, 64, 1), 256, 0, stream>>>(
      Xh + 1 * XSZ, nullptr, WThi + 1u * 1048576u, WTlo + 1u * 1048576u,
      1024, 1024, 1024, nullptr, Vhi, nullptr, 1024, 0, 0, 0);

  transpose_v_kernel<<<dim3(16, 32, 4), 256, 0, stream>>>(Vhi, VT);

  // scores = Q.K^T (raw), causal lower-triangle tiles only, f32 out
  gemm3_kernel<3, 0, true, false><<<dim3(16, 16, 4), 256, 0, stream>>>(
      Qhi, Qlo, Khi, Klo, 1024, 1024, 1024, Sc, nullptr, nullptr, 2048,
      (size_t)2048 * 1024, (size_t)2048 * 1024, (size_t)2048 * 2048);

  softmax_kernel<<<dim3(8192), 256, 0, stream>>>(Sc);

  // out = P.V (P bf16 pitch 4096, VT K-major), K-loop stops at diagonal
  gemm3_kernel<1, 0, false, true><<<dim3(8, 16, 4), 256, 0, stream>>>(
      (const unsigned short*)Sc, nullptr, VT, nullptr, 4096, 2048, 2048,
      out, nullptr, nullptr, 1024, (size_t)2048 * 4096, (size_t)1024 * 2048,
      (size_t)2048 * 1024);
}

// Round 3
// 315.197 us; speedup vs baseline: 1.2209x; 1.1484x over previous
//
#include <hip/hip_runtime.h>
#include <math.h>

using f32x4  = __attribute__((ext_vector_type(4))) float;
using bf16x8 = __attribute__((ext_vector_type(8))) short;
using u16x8  = __attribute__((ext_vector_type(8))) unsigned short;
using u16x4  = __attribute__((ext_vector_type(4))) unsigned short;

static __device__ __forceinline__ unsigned short f2bf(float f) {
  unsigned int u = __builtin_bit_cast(unsigned int, f);
  u += 0x7FFFu + ((u >> 16) & 1u);
  return (unsigned short)(u >> 16);
}
static __device__ __forceinline__ float bf2f(unsigned short h) {
  unsigned int u = ((unsigned int)h) << 16;
  return __builtin_bit_cast(float, u);
}

// async global->LDS, 16B per lane. LDS dest is wave-uniform base; HW appends
// lane*16.
static __device__ __forceinline__ void gll16(const void* g, void* l) {
  using GPtr = const unsigned int __attribute__((address_space(1)))*;
  using LPtr = unsigned int __attribute__((address_space(3)))*;
  __builtin_amdgcn_global_load_lds((GPtr)(unsigned long long)g,
                                   (LPtr)(unsigned)(unsigned long long)l,
                                   16, 0, 0);
}

// Stage one [128][64] bf16 tile with XOR-swizzled layout:
// LDS[row][slot] (slot = 16B unit) holds global column-slot (slot ^ (row&7)).
// Achieved by linear LDS dest + pre-swizzled global source column (rule #21).
// Wave w stages rows [32w, 32w+32).
static __device__ __forceinline__ void stage64(unsigned short* sdst,
                                               const unsigned short* g,
                                               size_t ld, int k0, int wave,
                                               int lane) {
  const int r = lane >> 3;                  // 0..7 row within octet
  const int c8 = lane & 7;                  // dest 16B slot 0..7
  const int scol = (c8 ^ r) << 3;           // pre-swizzled source column (elems)
#pragma unroll
  for (int i = 0; i < 4; ++i) {
    const unsigned short* gp = g + (size_t)(wave * 32 + i * 8 + r) * ld + (k0 + scol);
    unsigned short* lp = sdst + wave * 2048 + i * 512;  // wave-uniform
    gll16(gp, lp);
  }
}

// Swizzled fragment read: row-major [128][64], element (row, kko..kko+7).
static __device__ __forceinline__ bf16x8 frag_ld(const unsigned short* s,
                                                 int row, int kko) {
  return *(const bf16x8*)&s[row * 64 + (kko ^ ((row & 7) << 3))];
}

// ---------------------------------------------------------------------------
// W [1024 i][1024 o] f32  ->  WT_hi/WT_lo [1024 o][1024 i] bf16 (transposed)
// z order: 0=K, 1=Q, 2=V.
// ---------------------------------------------------------------------------
__global__ __launch_bounds__(256) void convert_w_kernel(
    const float* __restrict__ Wk, const float* __restrict__ Wq,
    const float* __restrict__ Wv, unsigned short* __restrict__ WThi,
    unsigned short* __restrict__ WTlo) {
  __shared__ float sW[64][65];
  const int z = blockIdx.z;
  const float* W = (z == 0) ? Wk : (z == 1) ? Wq : Wv;
  unsigned short* oh = WThi + (size_t)z * 1024 * 1024;
  unsigned short* ol = WTlo + (size_t)z * 1024 * 1024;
  const int ti = blockIdx.x * 64;
  const int tj = blockIdx.y * 64;
  const int tid = threadIdx.x;
#pragma unroll
  for (int it = 0; it < 4; ++it) {
    int idx = tid + it * 256;
    int r = idx >> 4, c = (idx & 15) << 2;
    f32x4 v = *(const f32x4*)&W[(size_t)(ti + r) * 1024 + tj + c];
    sW[r][c] = v[0]; sW[r][c + 1] = v[1]; sW[r][c + 2] = v[2]; sW[r][c + 3] = v[3];
  }
  __syncthreads();
#pragma unroll
  for (int it = 0; it < 4; ++it) {
    int idx = tid + it * 256;
    int ro = idx >> 4, ci = (idx & 15) << 2;
    u16x4 h, l;
#pragma unroll
    for (int e = 0; e < 4; ++e) {
      float v = sW[ci + e][ro];
      unsigned short hh = f2bf(v);
      h[e] = hh;
      l[e] = f2bf(v - bf2f(hh));
    }
    *(u16x4*)&oh[(size_t)(tj + ro) * 1024 + ti + ci] = h;
    *(u16x4*)&ol[(size_t)(tj + ro) * 1024 + ti + ci] = l;
  }
}

// ---------------------------------------------------------------------------
// X [8192 x 1024] f32 -> Xh (+Xl for z<2) bf16, same layout.
// z: 0=keys, 1=queries, 2=values. Xl slot = z (z<2 only).
// ---------------------------------------------------------------------------
__global__ __launch_bounds__(256) void convert_x_kernel(
    const float* __restrict__ Xk, const float* __restrict__ Xq,
    const float* __restrict__ Xv, unsigned short* __restrict__ H,
    unsigned short* __restrict__ L) {
  const int z = blockIdx.z;
  const float* X = (z == 0) ? Xk : (z == 1) ? Xq : Xv;
  const size_t base = ((size_t)blockIdx.x * 256 + threadIdx.x) * 8;
  float av[8];
  *(f32x4*)&av[0] = *(const f32x4*)&X[base];
  *(f32x4*)&av[4] = *(const f32x4*)&X[base + 4];
  u16x8 h, l;
#pragma unroll
  for (int e = 0; e < 8; ++e) {
    unsigned short hh = f2bf(av[e]);
    h[e] = hh;
    l[e] = f2bf(av[e] - bf2f(hh));
  }
  *(u16x8*)&H[(size_t)z * 8388608 + base] = h;
  if (z < 2) *(u16x8*)&L[(size_t)z * 8388608 + base] = l;
}

// ---------------------------------------------------------------------------
// Unified split-bf16 GEMM: 128x128 tile, BK=64, 4 waves, global_load_lds
// staging into XOR-swizzled [128][64] LDS tiles, 2 barriers per K-step.
// C = A * B^T, A rows = out rows, B rows = out cols, both K-major.
// NTERMS: 3 = AhBh+AhBl+AlBh ; 2 = AhBh+AhBl ; 1 = AhBh.
// EPI: 0 = f32 C ; 1 = bf16 hi+lo ; 2 = bf16 hi.
// PACKED: blockIdx.x is a packed lower-triangle tile index.
// PVK: K-loop ends at (bm+1)*128.
// ---------------------------------------------------------------------------
template <int NTERMS, int EPI, bool PACKED, bool PVK>
__global__ __launch_bounds__(256, 2) void gemm3_kernel(
    const unsigned short* __restrict__ Ah, const unsigned short* __restrict__ Al,
    const unsigned short* __restrict__ Bh, const unsigned short* __restrict__ Bl,
    size_t lda, size_t ldb, int K,
    float* __restrict__ Cf, unsigned short* __restrict__ Ch,
    unsigned short* __restrict__ Cl, size_t ldc,
    size_t abatch, size_t bbatch, size_t cbatch) {
  constexpr int NTILES = (NTERMS == 3) ? 4 : (NTERMS == 2) ? 3 : 2;
  __shared__ unsigned short smem[NTILES * 8192];
  int bm, bn;
  if constexpr (PACKED) {
    const int t = blockIdx.x;
    bm = (int)((sqrtf(8.f * (float)t + 1.f) - 1.f) * 0.5f);
    while ((bm + 1) * (bm + 2) / 2 <= t) ++bm;
    while (bm * (bm + 1) / 2 > t) --bm;
    bn = t - bm * (bm + 1) / 2;
  } else {
    bn = blockIdx.x;
    bm = blockIdx.y;
  }
  const int b = blockIdx.z;
  const int tid = threadIdx.x, lane = tid & 63, wave = tid >> 6;
  unsigned short* sAh = smem;
  unsigned short* sBh = smem + 8192;
  unsigned short* sBl = smem + 16384;  // NTERMS >= 2
  unsigned short* sAl = smem + 24576;  // NTERMS == 3
  const unsigned short* gA = Ah + abatch * b + (size_t)(bm * 128) * lda;
  const unsigned short* gB = Bh + bbatch * b + (size_t)(bn * 128) * ldb;
  const unsigned short* gAl2 =
      (NTERMS == 3) ? Al + abatch * b + (size_t)(bm * 128) * lda : nullptr;
  const unsigned short* gBl2 =
      (NTERMS >= 2) ? Bl + bbatch * b + (size_t)(bn * 128) * ldb : nullptr;
  const int kend = PVK ? (bm + 1) * 128 : K;
  f32x4 acc[4][4] = {};
  const int wr = (wave >> 1) << 6, wc = (wave & 1) << 6;
  const int frow = lane & 15, koff = (lane >> 4) << 3;
  for (int k0 = 0; k0 < kend; k0 += 64) {
    __syncthreads();  // all waves done reading previous tile
    stage64(sAh, gA, lda, k0, wave, lane);
    stage64(sBh, gB, ldb, k0, wave, lane);
    if constexpr (NTERMS >= 2) stage64(sBl, gBl2, ldb, k0, wave, lane);
    if constexpr (NTERMS == 3) stage64(sAl, gAl2, lda, k0, wave, lane);
    __syncthreads();  // staging complete
#pragma unroll
    for (int kk = 0; kk < 64; kk += 32) {
      const int kko = kk + koff;
      bf16x8 fBh[4], fBl[4];
#pragma unroll
      for (int j = 0; j < 4; ++j) {
        fBh[j] = frag_ld(sBh, wc + j * 16 + frow, kko);
        if constexpr (NTERMS >= 2) fBl[j] = frag_ld(sBl, wc + j * 16 + frow, kko);
      }
#pragma unroll
      for (int i = 0; i < 4; ++i) {
        const bf16x8 ah = frag_ld(sAh, wr + i * 16 + frow, kko);
        bf16x8 al = {};
        if constexpr (NTERMS == 3) al = frag_ld(sAl, wr + i * 16 + frow, kko);
#pragma unroll
        for (int j = 0; j < 4; ++j) {
          acc[i][j] = __builtin_amdgcn_mfma_f32_16x16x32_bf16(ah, fBh[j], acc[i][j], 0, 0, 0);
          if constexpr (NTERMS >= 2)
            acc[i][j] = __builtin_amdgcn_mfma_f32_16x16x32_bf16(ah, fBl[j], acc[i][j], 0, 0, 0);
          if constexpr (NTERMS == 3)
            acc[i][j] = __builtin_amdgcn_mfma_f32_16x16x32_bf16(al, fBh[j], acc[i][j], 0, 0, 0);
        }
      }
    }
  }
  const int erow = bm * 128 + wr + ((lane >> 4) << 2);
  const int ecol = bn * 128 + wc + frow;
  if constexpr (EPI == 0) {
    float* C = Cf + cbatch * b;
#pragma unroll
    for (int i = 0; i < 4; ++i)
#pragma unroll
      for (int j = 0; j < 4; ++j)
#pragma unroll
        for (int e = 0; e < 4; ++e)
          C[(size_t)(erow + i * 16 + e) * ldc + (ecol + j * 16)] = acc[i][j][e];
  } else {
    unsigned short* Cho = Ch + cbatch * b;
    unsigned short* Clo = (EPI == 1) ? Cl + cbatch * b : nullptr;
#pragma unroll
    for (int i = 0; i < 4; ++i)
#pragma unroll
      for (int j = 0; j < 4; ++j)
#pragma unroll
        for (int e = 0; e < 4; ++e) {
          size_t off = (size_t)(erow + i * 16 + e) * ldc + (ecol + j * 16);
          float v = acc[i][j][e];
          unsigned short hh = f2bf(v);
          Cho[off] = hh;
          if constexpr (EPI == 1) Clo[off] = f2bf(v - bf2f(hh));
        }
  }
}

// ---------------------------------------------------------------------------
// V [b][2048 s][1024 o] bf16 -> VT [b][1024 o][2048 s] bf16
// ---------------------------------------------------------------------------
__global__ __launch_bounds__(256) void transpose_v_kernel(
    const unsigned short* __restrict__ V, unsigned short* __restrict__ VT) {
  __shared__ unsigned short sV[64][72];
  const int ox = blockIdx.x, sy = blockIdx.y, b = blockIdx.z;
  const int tid = threadIdx.x;
#pragma unroll
  for (int it = 0; it < 2; ++it) {
    int idx = tid + it * 256;
    int r = idx >> 3, c8 = (idx & 7) << 3;
    u16x8 v = *(const u16x8*)&V[((size_t)b * 2048 + sy * 64 + r) * 1024 + ox * 64 + c8];
#pragma unroll
    for (int e = 0; e < 8; ++e) sV[r][c8 + e] = v[e];
  }
  __syncthreads();
#pragma unroll
  for (int it = 0; it < 2; ++it) {
    int idx = tid + it * 256;
    int ro = idx >> 3, cs = (idx & 7) << 3;
    u16x8 w;
#pragma unroll
    for (int e = 0; e < 8; ++e) w[e] = sV[cs + e][ro];
    *(u16x8*)&VT[((size_t)b * 1024 + ox * 64 + ro) * 2048 + sy * 64 + cs] = w;
  }
}

// ---------------------------------------------------------------------------
// Row softmax with causal mask + 1/sqrt(d) scale. Writes bf16 P in-place over
// the f32 scores buffer. Safe: reads complete before first barrier.
// ---------------------------------------------------------------------------
__global__ __launch_bounds__(256) void softmax_kernel(float* __restrict__ Sc) {
  const int row = blockIdx.x;  // b*2048 + q
  const int q = row & 2047;
  const int tid = threadIdx.x, lane = tid & 63, wave = tid >> 6;
  float* srow = Sc + (size_t)row * 2048;
  unsigned short* prow = (unsigned short*)srow;
  const int k0 = tid * 4, k1 = 1024 + tid * 4;
  f32x4 v0 = {}, v1 = {};
  if (k0 <= q) v0 = *(const f32x4*)(srow + k0);
  if (k1 <= q) v1 = *(const f32x4*)(srow + k1);
  float m = -3.0e38f;
#pragma unroll
  for (int e = 0; e < 4; ++e) {
    if (k0 + e <= q) m = fmaxf(m, v0[e]);
    if (k1 + e <= q) m = fmaxf(m, v1[e]);
  }
#pragma unroll
  for (int o = 32; o; o >>= 1) m = fmaxf(m, __shfl_xor(m, o));
  __shared__ float redm[4], reds[4];
  if (lane == 0) redm[wave] = m;
  __syncthreads();
  m = fmaxf(fmaxf(redm[0], redm[1]), fmaxf(redm[2], redm[3]));
  const float scale = 0.03125f;  // 1/sqrt(1024)
  float p[8];
  float s = 0.f;
#pragma unroll
  for (int e = 0; e < 4; ++e) {
    p[e] = (k0 + e <= q) ? __expf((v0[e] - m) * scale) : 0.f;
    p[4 + e] = (k1 + e <= q) ? __expf((v1[e] - m) * scale) : 0.f;
    s += p[e] + p[4 + e];
  }
#pragma unroll
  for (int o = 32; o; o >>= 1) s += __shfl_xor(s, o);
  if (lane == 0) reds[wave] = s;
  __syncthreads();
  s = reds[0] + reds[1] + reds[2] + reds[3];
  const float inv = 1.0f / s;
  u16x4 o0, o1;
#pragma unroll
  for (int e = 0; e < 4; ++e) {
    o0[e] = f2bf(p[e] * inv);
    o1[e] = f2bf(p[4 + e] * inv);
  }
  *(u16x4*)&prow[k0] = o0;
  *(u16x4*)&prow[k1] = o1;
}

// ---------------------------------------------------------------------------
extern "C" void kernel_launch(void* const* d_in, const int* in_sizes, int n_in,
                              void* d_out, int out_size, void* d_ws, size_t ws_size,
                              hipStream_t stream) {
  const float* Xk = (const float*)d_in[0];
  const float* Xv = (const float*)d_in[1];
  const float* Xq = (const float*)d_in[2];
  const float* Wk = (const float*)d_in[3];
  const float* Wv = (const float*)d_in[4];
  const float* Wq = (const float*)d_in[5];
  float* out = (float*)d_out;

  char* ws = (char*)d_ws;
  size_t off = 0;
  auto walloc = [&](size_t bytes) {
    void* p = ws + off;
    off += (bytes + 255) & ~(size_t)255;
    return p;
  };
  const size_t XSZ = 8192ull * 1024;  // elements per [8192x1024] matrix
  // X region (dead after projections): z order K=0, Q=1, V=2 for hi; K,Q for lo.
  unsigned short* Xh = (unsigned short*)walloc(3 * XSZ * 2);  // 48 MiB
  unsigned short* Xl = (unsigned short*)walloc(2 * XSZ * 2);  // 32 MiB (ends 80 MiB)
  unsigned short* WThi = (unsigned short*)walloc(3ull * 1024 * 1024 * 2);
  unsigned short* WTlo = (unsigned short*)walloc(3ull * 1024 * 1024 * 2);
  unsigned short* KQhi = (unsigned short*)walloc(2 * XSZ * 2);  // [Khi | Qhi]
  unsigned short* KQlo = (unsigned short*)walloc(2 * XSZ * 2);  // [Klo | Qlo]
  unsigned short* Vhi = (unsigned short*)walloc(XSZ * 2);
  // Aliases into the dead X region (written only after all projs complete):
  float* Sc = (float*)(ws + 0);                              // 64 MiB
  unsigned short* VT = (unsigned short*)(ws + 67108864ull);  // 16 MiB, ends 80 MiB

  convert_w_kernel<<<dim3(16, 16, 3), 256, 0, stream>>>(Wk, Wq, Wv, WThi, WTlo);
  convert_x_kernel<<<dim3(4096, 1, 3), 256, 0, stream>>>(Xk, Xq, Xv, Xh, Xl);

  // Fused K+Q projections (3-term, hi+lo out), batched over z: 0=K, 1=Q.
  gemm3_kernel<3, 1, false, false><<<dim3(8, 64, 2), 256, 0, stream>>>(
      Xh, Xl, WThi, WTlo, 1024, 1024, 1024, nullptr, KQhi, KQlo, 1024,
      XSZ, (size_t)1024 * 1024, XSZ);
  // V projection (2-term: bf16 X vs split W; hi out)
  gemm3_kernel<2, 2, false, false><<<dim3(8, 64, 1), 256, 0, stream>>>(
      Xh + 2 * XSZ, nullptr, WThi + 2u * 1048576u, WTlo + 2u * 1048576u,
      1024, 1024, 1024, nullptr, Vhi, nullptr, 1024, 0, 0, 0);

  transpose_v_kernel<<<dim3(16, 32, 4), 256, 0, stream>>>(Vhi, VT);

  // scores = Q.K^T (raw), packed lower-triangle tile grid, f32 out
  gemm3_kernel<3, 0, true, false><<<dim3(136, 1, 4), 256, 0, stream>>>(
      KQhi + XSZ, KQlo + XSZ, KQhi, KQlo, 1024, 1024, 1024, Sc, nullptr,
      nullptr, 2048, (size_t)2048 * 1024, (size_t)2048 * 1024,
      (size_t)2048 * 2048);

  softmax_kernel<<<dim3(8192), 256, 0, stream>>>(Sc);

  // out = P.V (P bf16 pitch 4096, VT K-major), K-loop stops at diagonal
  gemm3_kernel<1, 0, false, true><<<dim3(8, 16, 4), 256, 0, stream>>>(
      (const unsigned short*)Sc, nullptr, VT, nullptr, 4096, 2048, 2048,
      out, nullptr, nullptr, 1024, (size_t)2048 * 4096, (size_t)1024 * 2048,
      (size_t)2048 * 1024);
}